// Round 1
// baseline (5264.007 us; speedup 1.0000x reference)
//
#include <hip/hip_runtime.h>

// HyperbolicAttention: N=100000 nodes, C=128, H=8 heads, D=16, E=640000 edges.
// Pipeline: QKV GEMMs -> per-edge scores -> global per-head softmax -> scatter -> out GEMM.

#define TPB 256

// ---------------------------------------------------------------------------
// Generic Y = X @ W^T + b for [nrows,128] x [128,128]. fp32 VALU.
// Block: 256 threads, 128 rows x 128 cols tile; per-thread 8 rows x 8 cols.
// W staged in LDS transposed (wt[j][c] = W[c][j]); A streamed from global.
// ---------------------------------------------------------------------------
__global__ __launch_bounds__(256) void gemm128_kernel(
    const float* __restrict__ X, int nrows,
    const float* __restrict__ W, const float* __restrict__ bias,
    float* __restrict__ Y)
{
    __shared__ float wt[128][128];  // 64 KiB: wt[j][c] = W[c][j]
    const int tid  = threadIdx.x;
    const int row0 = blockIdx.x * 128;

    // Stage W transposed. idx -> (c = 4*(idx>>7)+(idx&3), j4 = (idx>>2)&31)
    // keeps global loads in 128B chunks and LDS write conflicts at ~4-way.
    {
        const float4* W4 = reinterpret_cast<const float4*>(W);
        #pragma unroll
        for (int t = 0; t < 16; ++t) {
            int idx = t * 256 + tid;
            int c   = 4 * (idx >> 7) + (idx & 3);
            int j4  = (idx >> 2) & 31;
            float4 v = W4[c * 32 + j4];
            wt[4*j4+0][c] = v.x;
            wt[4*j4+1][c] = v.y;
            wt[4*j4+2][c] = v.z;
            wt[4*j4+3][c] = v.w;
        }
    }
    __syncthreads();

    const int tx = tid & 15;   // col group: cols {4tx..4tx+3} U {64+4tx..64+4tx+3}
    const int ty = tid >> 4;   // row group: rows 8*ty..8*ty+7
    const int rbase = row0 + 8 * ty;
    const int c0 = 4 * tx;

    const float4* X4 = reinterpret_cast<const float4*>(X);
    float acc[8][8] = {};      // [row i][m]; m<4 -> col c0+m, m>=4 -> col 64+c0+(m-4)

    for (int j4 = 0; j4 < 32; ++j4) {
        float4 a4[8];
        #pragma unroll
        for (int i = 0; i < 8; ++i) {
            int rg = rbase + i;
            a4[i] = (rg < nrows) ? X4[(size_t)rg * 32 + j4]
                                 : make_float4(0.f, 0.f, 0.f, 0.f);
        }
        #pragma unroll
        for (int jj = 0; jj < 4; ++jj) {
            const int j = 4 * j4 + jj;
            float b[8];
            *(float4*)&b[0] = *(const float4*)&wt[j][c0];
            *(float4*)&b[4] = *(const float4*)&wt[j][64 + c0];
            #pragma unroll
            for (int i = 0; i < 8; ++i) {
                const float av = ((const float*)&a4[i])[jj];
                #pragma unroll
                for (int m = 0; m < 8; ++m) acc[i][m] += av * b[m];
            }
        }
    }

    float bv[8];
    *(float4*)&bv[0] = *(const float4*)&bias[c0];
    *(float4*)&bv[4] = *(const float4*)&bias[64 + c0];
    #pragma unroll
    for (int i = 0; i < 8; ++i) {
        int rg = rbase + i;
        if (rg < nrows) {
            float4 o0 = make_float4(acc[i][0]+bv[0], acc[i][1]+bv[1],
                                    acc[i][2]+bv[2], acc[i][3]+bv[3]);
            float4 o1 = make_float4(acc[i][4]+bv[4], acc[i][5]+bv[5],
                                    acc[i][6]+bv[6], acc[i][7]+bv[7]);
            float4* Y4 = reinterpret_cast<float4*>(Y + (size_t)rg * 128);
            Y4[tx]      = o0;
            Y4[16 + tx] = o1;
        }
    }
}

// ---------------------------------------------------------------------------
// edge_index may arrive as int64 (reference) or int32 (jax x64-disabled).
// Detect on device: for int64, every odd int32 slot (high word) is 0.
// ---------------------------------------------------------------------------
__global__ void detect_i64_kernel(const int* __restrict__ raw, int* __restrict__ flag)
{
    if (blockIdx.x == 0 && threadIdx.x == 0) {
        int odd_nonzero = 0;
        for (int i = 0; i < 128; ++i)
            if (raw[2 * i + 1] != 0) odd_nonzero = 1;
        *flag = odd_nonzero ? 0 : 1;  // 1 => int64 layout
    }
}

__global__ void conv_idx_kernel(const void* __restrict__ raw, int n,
                                const int* __restrict__ flag, int* __restrict__ out)
{
    int i = blockIdx.x * TPB + threadIdx.x;
    if (i >= n) return;
    if (*flag) out[i] = (int)((const long long*)raw)[i];
    else       out[i] = ((const int*)raw)[i];
}

// ---------------------------------------------------------------------------
// Per-edge, per-head dot products: S[e*8+h] = q[row[e],h,:] . k[col[e],h,:] / 4
// ---------------------------------------------------------------------------
__global__ void edge_scores_kernel(const float* __restrict__ Q, const float* __restrict__ K,
                                   const int* __restrict__ ei, int E,
                                   float* __restrict__ S)
{
    int idx = blockIdx.x * TPB + threadIdx.x;
    if (idx >= E * 8) return;
    int e = idx >> 3, h = idx & 7;
    int r = ei[e], c = ei[E + e];
    const float4* q4 = reinterpret_cast<const float4*>(Q) + (size_t)r * 32 + h * 4;
    const float4* k4 = reinterpret_cast<const float4*>(K) + (size_t)c * 32 + h * 4;
    float dot = 0.f;
    #pragma unroll
    for (int i = 0; i < 4; ++i) {
        float4 a = q4[i], b = k4[i];
        dot += a.x*b.x + a.y*b.y + a.z*b.z + a.w*b.w;
    }
    S[idx] = dot * 0.25f;  // 1/sqrt(16)
}

// ---------------------------------------------------------------------------
// Global per-head max over all E edges (softmax stabilization).
// Monotonic float->uint map so atomicMax(uint) works; memset-0 init == -inf.
// ---------------------------------------------------------------------------
__device__ __forceinline__ unsigned f2u_mono(float f) {
    unsigned b = __float_as_uint(f);
    return (b & 0x80000000u) ? ~b : (b | 0x80000000u);
}
__device__ __forceinline__ float u2f_mono(unsigned u) {
    return (u & 0x80000000u) ? __uint_as_float(u & 0x7fffffffu) : __uint_as_float(~u);
}

__global__ void head_max_kernel(const float* __restrict__ S, int total,
                                unsigned* __restrict__ Mu)
{
    int t = threadIdx.x;
    long long idx = (long long)blockIdx.x * TPB + t;
    long long stride = (long long)gridDim.x * TPB;   // multiple of 8 -> h class fixed = t&7
    float m = -3.0e38f;
    for (; idx < total; idx += stride) m = fmaxf(m, S[idx]);
    __shared__ unsigned sm[TPB];
    sm[t] = f2u_mono(m);
    __syncthreads();
    for (int off = 128; off >= 8; off >>= 1) {
        if (t < off) sm[t] = max(sm[t], sm[t + off]);
        __syncthreads();
    }
    if (t < 8) atomicMax(&Mu[t], sm[t]);
}

// ---------------------------------------------------------------------------
// P = exp(S - M[h]) written in place; Z[h] += block partial sums.
// ---------------------------------------------------------------------------
__global__ void exp_sum_kernel(float* __restrict__ S, int total,
                               const unsigned* __restrict__ Mu, float* __restrict__ Z)
{
    int t = threadIdx.x;
    float M = u2f_mono(Mu[t & 7]);
    long long idx = (long long)blockIdx.x * TPB + t;
    long long stride = (long long)gridDim.x * TPB;
    float sum = 0.f;
    for (; idx < total; idx += stride) {
        float p = __expf(S[idx] - M);
        S[idx] = p;
        sum += p;
    }
    __shared__ float sm[TPB];
    sm[t] = sum;
    __syncthreads();
    for (int off = 128; off >= 8; off >>= 1) {
        if (t < off) sm[t] += sm[t + off];
        __syncthreads();
    }
    if (t < 8) atomicAdd(&Z[t], sm[t]);
}

// ---------------------------------------------------------------------------
// Scatter: acc[row[e], h, :] += (P[e,h]/Z[h]) * V[col[e], h, :]
// ---------------------------------------------------------------------------
__global__ void scatter_kernel(const float* __restrict__ P, const float* __restrict__ V,
                               const int* __restrict__ ei, int E,
                               const float* __restrict__ Z, float* __restrict__ acc)
{
    int idx = blockIdx.x * TPB + threadIdx.x;
    if (idx >= E * 8) return;
    int e = idx >> 3, h = idx & 7;
    int r = ei[e], c = ei[E + e];
    float w = P[idx] / Z[h];
    const float4* v4 = reinterpret_cast<const float4*>(V) + (size_t)c * 32 + h * 4;
    float* a = acc + (size_t)r * 128 + h * 16;
    #pragma unroll
    for (int i = 0; i < 4; ++i) {
        float4 v = v4[i];
        atomicAdd(a + 4*i + 0, w * v.x);
        atomicAdd(a + 4*i + 1, w * v.y);
        atomicAdd(a + 4*i + 2, w * v.z);
        atomicAdd(a + 4*i + 3, w * v.w);
    }
}

// ---------------------------------------------------------------------------
extern "C" void kernel_launch(void* const* d_in, const int* in_sizes, int n_in,
                              void* d_out, int out_size, void* d_ws, size_t ws_size,
                              hipStream_t stream)
{
    const float* feat = (const float*)d_in[0];
    const void*  eraw = d_in[1];
    const float* Wq = (const float*)d_in[2];
    const float* bq = (const float*)d_in[3];
    const float* Wk = (const float*)d_in[4];
    const float* bk = (const float*)d_in[5];
    const float* Wv = (const float*)d_in[6];
    const float* bv = (const float*)d_in[7];
    const float* Wo = (const float*)d_in[8];
    const float* bo = (const float*)d_in[9];

    const int N = in_sizes[0] / 128;
    const int E = in_sizes[1] / 2;
    const size_t NC = (size_t)N * 128;
    const int EH = E * 8;

    // Workspace layout (floats)
    float* Q   = (float*)d_ws;
    float* Km  = Q   + NC;
    float* Vm  = Km  + NC;
    float* ACC = Vm  + NC;
    float* P   = ACC + NC;            // E*8 scores -> exp weights (in place)
    int*   EI  = (int*)(P + EH);      // normalized int32 indices, 2*E
    unsigned* Mu   = (unsigned*)(EI + 2 * E); // 8 per-head max (monotone-uint)
    float*    Z    = (float*)(Mu + 8);        // 8 per-head softmax denominators
    int*      flag = (int*)(Z + 8);           // int64-detect flag

    // Re-init scratch every call (harness poisons once, never restores).
    hipMemsetAsync(ACC, 0, NC * sizeof(float), stream);
    hipMemsetAsync(Mu, 0, 8 * sizeof(unsigned) + 8 * sizeof(float) + sizeof(int), stream);

    // Normalize edge_index to int32.
    detect_i64_kernel<<<1, 64, 0, stream>>>((const int*)eraw, flag);
    conv_idx_kernel<<<(2 * E + TPB - 1) / TPB, TPB, 0, stream>>>(eraw, 2 * E, flag, EI);

    // Q/K/V projections.
    const int gb = (N + 127) / 128;
    gemm128_kernel<<<gb, TPB, 0, stream>>>(feat, N, Wq, bq, Q);
    gemm128_kernel<<<gb, TPB, 0, stream>>>(feat, N, Wk, bk, Km);
    gemm128_kernel<<<gb, TPB, 0, stream>>>(feat, N, Wv, bv, Vm);

    // Edge scores, global per-head softmax pieces.
    const int eb = (EH + TPB - 1) / TPB;
    edge_scores_kernel<<<eb, TPB, 0, stream>>>(Q, Km, EI, E, P);
    head_max_kernel<<<2048, TPB, 0, stream>>>(P, EH, Mu);
    exp_sum_kernel<<<2048, TPB, 0, stream>>>(P, EH, Mu, Z);

    // Weighted scatter-add of V into ACC.
    scatter_kernel<<<eb, TPB, 0, stream>>>(P, Vm, EI, E, Z, ACC);

    // Output projection.
    gemm128_kernel<<<gb, TPB, 0, stream>>>(ACC, N, Wo, bo, (float*)d_out);
}

// Round 2
// 806.499 us; speedup vs baseline: 6.5270x; 6.5270x over previous
//
#include <hip/hip_runtime.h>

// HyperbolicAttention: N=100000 nodes, C=128, H=8 heads, D=16, E=640000 edges.
// Pipeline: QKV GEMMs -> per-edge scores -> global per-head softmax ->
//           CSR(dest)-binned gather segment-sum -> out GEMM.

#define TPB 256

// ---------------------------------------------------------------------------
// Generic Y = X @ W^T + b for [nrows,128] x [128,128]. fp32 VALU.
// Block: 256 threads, 128 rows x 128 cols tile; per-thread 8 rows x 8 cols.
// W staged in LDS transposed (wt[j][c] = W[c][j]); A streamed from global.
// ---------------------------------------------------------------------------
__global__ __launch_bounds__(256) void gemm128_kernel(
    const float* __restrict__ X, int nrows,
    const float* __restrict__ W, const float* __restrict__ bias,
    float* __restrict__ Y)
{
    __shared__ float wt[128][128];  // 64 KiB: wt[j][c] = W[c][j]
    const int tid  = threadIdx.x;
    const int row0 = blockIdx.x * 128;

    {
        const float4* W4 = reinterpret_cast<const float4*>(W);
        #pragma unroll
        for (int t = 0; t < 16; ++t) {
            int idx = t * 256 + tid;
            int c   = 4 * (idx >> 7) + (idx & 3);
            int j4  = (idx >> 2) & 31;
            float4 v = W4[c * 32 + j4];
            wt[4*j4+0][c] = v.x;
            wt[4*j4+1][c] = v.y;
            wt[4*j4+2][c] = v.z;
            wt[4*j4+3][c] = v.w;
        }
    }
    __syncthreads();

    const int tx = tid & 15;
    const int ty = tid >> 4;
    const int rbase = row0 + 8 * ty;
    const int c0 = 4 * tx;

    const float4* X4 = reinterpret_cast<const float4*>(X);
    float acc[8][8] = {};

    for (int j4 = 0; j4 < 32; ++j4) {
        float4 a4[8];
        #pragma unroll
        for (int i = 0; i < 8; ++i) {
            int rg = rbase + i;
            a4[i] = (rg < nrows) ? X4[(size_t)rg * 32 + j4]
                                 : make_float4(0.f, 0.f, 0.f, 0.f);
        }
        #pragma unroll
        for (int jj = 0; jj < 4; ++jj) {
            const int j = 4 * j4 + jj;
            float b[8];
            *(float4*)&b[0] = *(const float4*)&wt[j][c0];
            *(float4*)&b[4] = *(const float4*)&wt[j][64 + c0];
            #pragma unroll
            for (int i = 0; i < 8; ++i) {
                const float av = ((const float*)&a4[i])[jj];
                #pragma unroll
                for (int m = 0; m < 8; ++m) acc[i][m] += av * b[m];
            }
        }
    }

    float bv[8];
    *(float4*)&bv[0] = *(const float4*)&bias[c0];
    *(float4*)&bv[4] = *(const float4*)&bias[64 + c0];
    #pragma unroll
    for (int i = 0; i < 8; ++i) {
        int rg = rbase + i;
        if (rg < nrows) {
            float4 o0 = make_float4(acc[i][0]+bv[0], acc[i][1]+bv[1],
                                    acc[i][2]+bv[2], acc[i][3]+bv[3]);
            float4 o1 = make_float4(acc[i][4]+bv[4], acc[i][5]+bv[5],
                                    acc[i][6]+bv[6], acc[i][7]+bv[7]);
            float4* Y4 = reinterpret_cast<float4*>(Y + (size_t)rg * 128);
            Y4[tx]      = o0;
            Y4[16 + tx] = o1;
        }
    }
}

// ---------------------------------------------------------------------------
// edge_index may arrive as int64 (reference) or int32. Detect on device.
// ---------------------------------------------------------------------------
__global__ void detect_i64_kernel(const int* __restrict__ raw, int* __restrict__ flag)
{
    if (blockIdx.x == 0 && threadIdx.x == 0) {
        int odd_nonzero = 0;
        for (int i = 0; i < 128; ++i)
            if (raw[2 * i + 1] != 0) odd_nonzero = 1;
        *flag = odd_nonzero ? 0 : 1;  // 1 => int64 layout
    }
}

__global__ void conv_idx_kernel(const void* __restrict__ raw, int n,
                                const int* __restrict__ flag, int* __restrict__ out)
{
    int i = blockIdx.x * TPB + threadIdx.x;
    if (i >= n) return;
    if (*flag) out[i] = (int)((const long long*)raw)[i];
    else       out[i] = ((const int*)raw)[i];
}

// ---------------------------------------------------------------------------
// Per-edge, per-head dot products: S[e*8+h] = q[row[e],h,:] . k[col[e],h,:] / 4
// ---------------------------------------------------------------------------
__global__ void edge_scores_kernel(const float* __restrict__ Q, const float* __restrict__ K,
                                   const int* __restrict__ ei, int E,
                                   float* __restrict__ S)
{
    int idx = blockIdx.x * TPB + threadIdx.x;
    if (idx >= E * 8) return;
    int e = idx >> 3, h = idx & 7;
    int r = ei[e], c = ei[E + e];
    const float4* q4 = reinterpret_cast<const float4*>(Q) + (size_t)r * 32 + h * 4;
    const float4* k4 = reinterpret_cast<const float4*>(K) + (size_t)c * 32 + h * 4;
    float dot = 0.f;
    #pragma unroll
    for (int i = 0; i < 4; ++i) {
        float4 a = q4[i], b = k4[i];
        dot += a.x*b.x + a.y*b.y + a.z*b.z + a.w*b.w;
    }
    S[idx] = dot * 0.25f;  // 1/sqrt(16)
}

// ---------------------------------------------------------------------------
// Global per-head softmax pieces (max then exp+sum).
// ---------------------------------------------------------------------------
__device__ __forceinline__ unsigned f2u_mono(float f) {
    unsigned b = __float_as_uint(f);
    return (b & 0x80000000u) ? ~b : (b | 0x80000000u);
}
__device__ __forceinline__ float u2f_mono(unsigned u) {
    return (u & 0x80000000u) ? __uint_as_float(u & 0x7fffffffu) : __uint_as_float(~u);
}

__global__ void head_max_kernel(const float* __restrict__ S, int total,
                                unsigned* __restrict__ Mu)
{
    int t = threadIdx.x;
    long long idx = (long long)blockIdx.x * TPB + t;
    long long stride = (long long)gridDim.x * TPB;
    float m = -3.0e38f;
    for (; idx < total; idx += stride) m = fmaxf(m, S[idx]);
    __shared__ unsigned sm[TPB];
    sm[t] = f2u_mono(m);
    __syncthreads();
    for (int off = 128; off >= 8; off >>= 1) {
        if (t < off) sm[t] = max(sm[t], sm[t + off]);
        __syncthreads();
    }
    if (t < 8) atomicMax(&Mu[t], sm[t]);
}

__global__ void exp_sum_kernel(float* __restrict__ S, int total,
                               const unsigned* __restrict__ Mu, float* __restrict__ Z)
{
    int t = threadIdx.x;
    float M = u2f_mono(Mu[t & 7]);
    long long idx = (long long)blockIdx.x * TPB + t;
    long long stride = (long long)gridDim.x * TPB;
    float sum = 0.f;
    for (; idx < total; idx += stride) {
        float p = __expf(S[idx] - M);
        S[idx] = p;
        sum += p;
    }
    __shared__ float sm[TPB];
    sm[t] = sum;
    __syncthreads();
    for (int off = 128; off >= 8; off >>= 1) {
        if (t < off) sm[t] += sm[t + off];
        __syncthreads();
    }
    if (t < 8) atomicAdd(&Z[t], sm[t]);
}

// ---------------------------------------------------------------------------
// CSR build: histogram by destination row, exclusive scan, binned fill.
// ---------------------------------------------------------------------------
__global__ void hist_kernel(const int* __restrict__ rows, int E, int* __restrict__ deg)
{
    int e = blockIdx.x * TPB + threadIdx.x;
    if (e < E) atomicAdd(&deg[rows[e]], 1);
}

// Block-local exclusive scan (256/block); block totals to bsum.
__global__ void scan1_kernel(const int* __restrict__ deg, int n,
                             int* __restrict__ rowstart, int* __restrict__ bsum)
{
    __shared__ int sm[TPB];
    int t = threadIdx.x;
    int gid = blockIdx.x * TPB + t;
    int v = (gid < n) ? deg[gid] : 0;
    sm[t] = v;
    __syncthreads();
    for (int off = 1; off < TPB; off <<= 1) {
        int x = (t >= off) ? sm[t - off] : 0;
        __syncthreads();
        sm[t] += x;
        __syncthreads();
    }
    if (gid < n) rowstart[gid] = sm[t] - v;  // block-local exclusive
    if (t == TPB - 1) bsum[blockIdx.x] = sm[t];
}

// Single-block exclusive scan of block sums (nb <= 512).
__global__ void scan2_kernel(int* __restrict__ bsum, int nb)
{
    __shared__ int sm[512];
    int t = threadIdx.x;
    int v = (t < nb) ? bsum[t] : 0;
    sm[t] = v;
    __syncthreads();
    for (int off = 1; off < 512; off <<= 1) {
        int x = (t >= off) ? sm[t - off] : 0;
        __syncthreads();
        sm[t] += x;
        __syncthreads();
    }
    if (t < nb) bsum[t] = sm[t] - v;
}

__global__ void scan3_kernel(int* __restrict__ rowstart, int n, int E,
                             const int* __restrict__ bsum)
{
    int gid = blockIdx.x * TPB + threadIdx.x;
    if (gid < n) rowstart[gid] += bsum[blockIdx.x];
    if (gid == 0) rowstart[n] = E;
}

__global__ void fill_kernel(const int* __restrict__ rows, int E,
                            int* __restrict__ cursor, int* __restrict__ elist)
{
    int e = blockIdx.x * TPB + threadIdx.x;
    if (e >= E) return;
    int pos = atomicAdd(&cursor[rows[e]], 1);
    elist[pos] = e;
}

// ---------------------------------------------------------------------------
// Gather segment-sum: thread = (node, head).
// out[node,h,:] = sum over edges e with row[e]==node of (P[e,h]/Z[h]) * V[col[e],h,:]
// ---------------------------------------------------------------------------
__global__ __launch_bounds__(256) void gather_kernel(
    const float* __restrict__ P, const float* __restrict__ V,
    const int* __restrict__ cols,      // EI + E
    const int* __restrict__ rowstart, const int* __restrict__ elist,
    const float* __restrict__ Z, int N,
    float* __restrict__ out)
{
    int idx = blockIdx.x * TPB + threadIdx.x;
    if (idx >= N * 8) return;
    int node = idx >> 3, h = idx & 7;
    float invZ = 1.0f / Z[h];
    int p0 = rowstart[node], p1 = rowstart[node + 1];

    float4 a0 = make_float4(0,0,0,0), a1 = a0, a2 = a0, a3 = a0;
    for (int p = p0; p < p1; ++p) {
        int e = elist[p];
        int c = cols[e];
        float w = P[e * 8 + h] * invZ;
        const float4* v4 = reinterpret_cast<const float4*>(V) + (size_t)c * 32 + h * 4;
        float4 v0 = v4[0], v1 = v4[1], v2 = v4[2], v3 = v4[3];
        a0.x += w*v0.x; a0.y += w*v0.y; a0.z += w*v0.z; a0.w += w*v0.w;
        a1.x += w*v1.x; a1.y += w*v1.y; a1.z += w*v1.z; a1.w += w*v1.w;
        a2.x += w*v2.x; a2.y += w*v2.y; a2.z += w*v2.z; a2.w += w*v2.w;
        a3.x += w*v3.x; a3.y += w*v3.y; a3.z += w*v3.z; a3.w += w*v3.w;
    }
    float4* o4 = reinterpret_cast<float4*>(out) + (size_t)node * 32 + h * 4;
    o4[0] = a0; o4[1] = a1; o4[2] = a2; o4[3] = a3;
}

// ---------------------------------------------------------------------------
extern "C" void kernel_launch(void* const* d_in, const int* in_sizes, int n_in,
                              void* d_out, int out_size, void* d_ws, size_t ws_size,
                              hipStream_t stream)
{
    const float* feat = (const float*)d_in[0];
    const void*  eraw = d_in[1];
    const float* Wq = (const float*)d_in[2];
    const float* bq = (const float*)d_in[3];
    const float* Wk = (const float*)d_in[4];
    const float* bk = (const float*)d_in[5];
    const float* Wv = (const float*)d_in[6];
    const float* bv = (const float*)d_in[7];
    const float* Wo = (const float*)d_in[8];
    const float* bo = (const float*)d_in[9];

    const int N = in_sizes[0] / 128;
    const int E = in_sizes[1] / 2;
    const size_t NC = (size_t)N * 128;
    const int EH = E * 8;

    // Workspace layout (floats)
    float* Q   = (float*)d_ws;
    float* Km  = Q   + NC;
    float* Vm  = Km  + NC;
    float* ACC = Vm  + NC;
    float* P   = ACC + NC;            // E*8 scores -> exp weights (in place)
    int*   EI  = (int*)(P + EH);      // normalized int32 indices, 2*E
    unsigned* Mu   = (unsigned*)(EI + 2 * E);
    float*    Z    = (float*)(Mu + 8);
    int*      flag = (int*)(Z + 8);

    // CSR structures alias the Q buffer (Q is dead after edge_scores).
    int* deg      = (int*)Q;              // N
    int* rowstart = deg + N;              // N+1
    int* cursor   = rowstart + N + 1;     // N
    int* bsum     = cursor + N;           // <=512
    int* elist    = bsum + 512;           // E

    hipMemsetAsync(Mu, 0, 8 * sizeof(unsigned) + 8 * sizeof(float) + sizeof(int), stream);

    // Normalize edge_index to int32.
    detect_i64_kernel<<<1, 64, 0, stream>>>((const int*)eraw, flag);
    conv_idx_kernel<<<(2 * E + TPB - 1) / TPB, TPB, 0, stream>>>(eraw, 2 * E, flag, EI);

    // Q/K/V projections.
    const int gb = (N + 127) / 128;
    gemm128_kernel<<<gb, TPB, 0, stream>>>(feat, N, Wq, bq, Q);
    gemm128_kernel<<<gb, TPB, 0, stream>>>(feat, N, Wk, bk, Km);
    gemm128_kernel<<<gb, TPB, 0, stream>>>(feat, N, Wv, bv, Vm);

    // Edge scores (uses Q, K).
    const int eb = (EH + TPB - 1) / TPB;
    edge_scores_kernel<<<eb, TPB, 0, stream>>>(Q, Km, EI, E, P);

    // CSR build (Q region now reusable).
    const int ebE = (E + TPB - 1) / TPB;
    const int nbS = (N + TPB - 1) / TPB;
    hipMemsetAsync(deg, 0, (size_t)N * sizeof(int), stream);
    hist_kernel<<<ebE, TPB, 0, stream>>>(EI, E, deg);
    scan1_kernel<<<nbS, TPB, 0, stream>>>(deg, N, rowstart, bsum);
    scan2_kernel<<<1, 512, 0, stream>>>(bsum, nbS);
    scan3_kernel<<<nbS, TPB, 0, stream>>>(rowstart, N, E, bsum);
    hipMemcpyAsync(cursor, rowstart, (size_t)N * sizeof(int),
                   hipMemcpyDeviceToDevice, stream);
    fill_kernel<<<ebE, TPB, 0, stream>>>(EI, E, cursor, elist);

    // Global per-head softmax.
    head_max_kernel<<<2048, TPB, 0, stream>>>(P, EH, Mu);
    exp_sum_kernel<<<2048, TPB, 0, stream>>>(P, EH, Mu, Z);

    // Gather segment-sum into ACC.
    const int gbN = (N * 8 + TPB - 1) / TPB;
    gather_kernel<<<gbN, TPB, 0, stream>>>(P, Vm, EI + E, rowstart, elist, Z, N, ACC);

    // Output projection.
    gemm128_kernel<<<gb, TPB, 0, stream>>>(ACC, N, Wo, bo, (float*)d_out);
}

// Round 3
// 512.474 us; speedup vs baseline: 10.2718x; 1.5737x over previous
//
#include <hip/hip_runtime.h>

// HyperbolicAttention: N=100000 nodes, C=128, H=8 heads, D=16, E=640000 edges.
// Pipeline: fused QKV bf16-MFMA GEMM -> per-edge scores -> global per-head
//           softmax -> CSR(dest)-binned gather segment-sum -> out MFMA GEMM.

#define TPB 256

typedef __attribute__((ext_vector_type(8))) short short8;
typedef __attribute__((ext_vector_type(4))) float f32x4;

// fp32 -> bf16 round-to-nearest-even
__device__ __forceinline__ short f2bf(float f) {
    unsigned u = __float_as_uint(f);
    u += 0x7fffu + ((u >> 16) & 1u);
    return (short)(u >> 16);
}

// ---------------------------------------------------------------------------
// Convert the four 128x128 fp32 weight matrices to bf16 (row-major, packed).
// ---------------------------------------------------------------------------
__global__ void wconv_kernel(const float* __restrict__ W0, const float* __restrict__ W1,
                             const float* __restrict__ W2, const float* __restrict__ W3,
                             short* __restrict__ out)
{
    int i = blockIdx.x * TPB + threadIdx.x;   // 0..65535
    if (i >= 65536) return;
    const float* W = (i < 16384) ? W0 : (i < 32768) ? W1 : (i < 49152) ? W2 : W3;
    out[i] = f2bf(W[i & 16383]);
}

// ---------------------------------------------------------------------------
// Y_w = X @ W_w^T + b_w for NW weight matrices, X:[nrows,128], W bf16.
// mfma_f32_16x16x32_bf16. Block = 4 waves; wave owns 16 rows x 128 cols.
// A-frag: lane reads X[rowbase+(l&15)][kc*32+(l>>4)*8 ..+7] (fp32->bf16).
// B-frag: lane reads Wbf[(n*16+(l&15))*128 + kc*32+(l>>4)*8] (16B short8).
// D: row=(l>>4)*4+j, col=l&15  [guide §3, m89-verified].
// ---------------------------------------------------------------------------
template<int NW>
__global__ __launch_bounds__(256) void gemm_mfma_kernel(
    const float* __restrict__ X, int nrows,
    const short* __restrict__ WB,  // NW x [128][128] bf16
    const float* __restrict__ b0, const float* __restrict__ b1, const float* __restrict__ b2,
    float* __restrict__ y0, float* __restrict__ y1, float* __restrict__ y2)
{
    const int tid  = threadIdx.x;
    const int wid  = tid >> 6;
    const int lane = tid & 63;
    const int l15  = lane & 15;
    const int lh   = lane >> 4;
    const int rowbase = blockIdx.x * 64 + wid * 16;

    const float* bias[3] = { b0, b1, b2 };
    float*       outs[3] = { y0, y1, y2 };

    f32x4 acc[NW][8];
    #pragma unroll
    for (int w = 0; w < NW; ++w)
        #pragma unroll
        for (int n = 0; n < 8; ++n) acc[w][n] = (f32x4)0.f;

    const int arow = rowbase + l15;
    const bool rvalid = arow < nrows;
    const float4* Xr = reinterpret_cast<const float4*>(X + (size_t)arow * 128);

    #pragma unroll
    for (int kc = 0; kc < 4; ++kc) {
        short8 afrag = (short8)(short)0;
        if (rvalid) {
            float4 x0 = Xr[kc*8 + lh*2 + 0];
            float4 x1 = Xr[kc*8 + lh*2 + 1];
            afrag[0]=f2bf(x0.x); afrag[1]=f2bf(x0.y); afrag[2]=f2bf(x0.z); afrag[3]=f2bf(x0.w);
            afrag[4]=f2bf(x1.x); afrag[5]=f2bf(x1.y); afrag[6]=f2bf(x1.z); afrag[7]=f2bf(x1.w);
        }
        #pragma unroll
        for (int w = 0; w < NW; ++w) {
            #pragma unroll
            for (int n = 0; n < 8; ++n) {
                short8 bfrag = *reinterpret_cast<const short8*>(
                    WB + ((size_t)w << 14) + (size_t)(n*16 + l15)*128 + kc*32 + lh*8);
                acc[w][n] = __builtin_amdgcn_mfma_f32_16x16x32_bf16(
                                afrag, bfrag, acc[w][n], 0, 0, 0);
            }
        }
    }

    #pragma unroll
    for (int w = 0; w < NW; ++w) {
        float* Y = outs[w];
        #pragma unroll
        for (int n = 0; n < 8; ++n) {
            float bv = bias[w][n*16 + l15];
            #pragma unroll
            for (int j = 0; j < 4; ++j) {
                int r = rowbase + lh*4 + j;
                if (r < nrows) Y[(size_t)r*128 + n*16 + l15] = acc[w][n][j] + bv;
            }
        }
    }
}

// ---------------------------------------------------------------------------
// edge_index may arrive as int64 (reference) or int32. Detect on device.
// ---------------------------------------------------------------------------
__global__ void detect_i64_kernel(const int* __restrict__ raw, int* __restrict__ flag)
{
    if (blockIdx.x == 0 && threadIdx.x == 0) {
        int odd_nonzero = 0;
        for (int i = 0; i < 128; ++i)
            if (raw[2 * i + 1] != 0) odd_nonzero = 1;
        *flag = odd_nonzero ? 0 : 1;  // 1 => int64 layout
    }
}

__global__ void conv_idx_kernel(const void* __restrict__ raw, int n,
                                const int* __restrict__ flag, int* __restrict__ out)
{
    int i = blockIdx.x * TPB + threadIdx.x;
    if (i >= n) return;
    if (*flag) out[i] = (int)((const long long*)raw)[i];
    else       out[i] = ((const int*)raw)[i];
}

// ---------------------------------------------------------------------------
// Per-edge, per-head dot products: S[e*8+h] = q[row[e],h,:] . k[col[e],h,:] / 4
// ---------------------------------------------------------------------------
__global__ void edge_scores_kernel(const float* __restrict__ Q, const float* __restrict__ K,
                                   const int* __restrict__ ei, int E,
                                   float* __restrict__ S)
{
    int idx = blockIdx.x * TPB + threadIdx.x;
    if (idx >= E * 8) return;
    int e = idx >> 3, h = idx & 7;
    int r = ei[e], c = ei[E + e];
    const float4* q4 = reinterpret_cast<const float4*>(Q) + (size_t)r * 32 + h * 4;
    const float4* k4 = reinterpret_cast<const float4*>(K) + (size_t)c * 32 + h * 4;
    float dot = 0.f;
    #pragma unroll
    for (int i = 0; i < 4; ++i) {
        float4 a = q4[i], b = k4[i];
        dot += a.x*b.x + a.y*b.y + a.z*b.z + a.w*b.w;
    }
    S[idx] = dot * 0.25f;  // 1/sqrt(16)
}

// ---------------------------------------------------------------------------
// Global per-head softmax pieces (max then exp+sum).
// ---------------------------------------------------------------------------
__device__ __forceinline__ unsigned f2u_mono(float f) {
    unsigned b = __float_as_uint(f);
    return (b & 0x80000000u) ? ~b : (b | 0x80000000u);
}
__device__ __forceinline__ float u2f_mono(unsigned u) {
    return (u & 0x80000000u) ? __uint_as_float(u & 0x7fffffffu) : __uint_as_float(~u);
}

__global__ void head_max_kernel(const float* __restrict__ S, int total,
                                unsigned* __restrict__ Mu)
{
    int t = threadIdx.x;
    long long idx = (long long)blockIdx.x * TPB + t;
    long long stride = (long long)gridDim.x * TPB;
    float m = -3.0e38f;
    for (; idx < total; idx += stride) m = fmaxf(m, S[idx]);
    __shared__ unsigned sm[TPB];
    sm[t] = f2u_mono(m);
    __syncthreads();
    for (int off = 128; off >= 8; off >>= 1) {
        if (t < off) sm[t] = max(sm[t], sm[t + off]);
        __syncthreads();
    }
    if (t < 8) atomicMax(&Mu[t], sm[t]);
}

__global__ void exp_sum_kernel(float* __restrict__ S, int total,
                               const unsigned* __restrict__ Mu, float* __restrict__ Z)
{
    int t = threadIdx.x;
    float M = u2f_mono(Mu[t & 7]);
    long long idx = (long long)blockIdx.x * TPB + t;
    long long stride = (long long)gridDim.x * TPB;
    float sum = 0.f;
    for (; idx < total; idx += stride) {
        float p = __expf(S[idx] - M);
        S[idx] = p;
        sum += p;
    }
    __shared__ float sm[TPB];
    sm[t] = sum;
    __syncthreads();
    for (int off = 128; off >= 8; off >>= 1) {
        if (t < off) sm[t] += sm[t + off];
        __syncthreads();
    }
    if (t < 8) atomicAdd(&Z[t], sm[t]);
}

// ---------------------------------------------------------------------------
// CSR build: histogram by destination row, exclusive scan, binned fill.
// ---------------------------------------------------------------------------
__global__ void hist_kernel(const int* __restrict__ rows, int E, int* __restrict__ deg)
{
    int e = blockIdx.x * TPB + threadIdx.x;
    if (e < E) atomicAdd(&deg[rows[e]], 1);
}

__global__ void scan1_kernel(const int* __restrict__ deg, int n,
                             int* __restrict__ rowstart, int* __restrict__ bsum)
{
    __shared__ int sm[TPB];
    int t = threadIdx.x;
    int gid = blockIdx.x * TPB + t;
    int v = (gid < n) ? deg[gid] : 0;
    sm[t] = v;
    __syncthreads();
    for (int off = 1; off < TPB; off <<= 1) {
        int x = (t >= off) ? sm[t - off] : 0;
        __syncthreads();
        sm[t] += x;
        __syncthreads();
    }
    if (gid < n) rowstart[gid] = sm[t] - v;
    if (t == TPB - 1) bsum[blockIdx.x] = sm[t];
}

__global__ void scan2_kernel(int* __restrict__ bsum, int nb)
{
    __shared__ int sm[512];
    int t = threadIdx.x;
    int v = (t < nb) ? bsum[t] : 0;
    sm[t] = v;
    __syncthreads();
    for (int off = 1; off < 512; off <<= 1) {
        int x = (t >= off) ? sm[t - off] : 0;
        __syncthreads();
        sm[t] += x;
        __syncthreads();
    }
    if (t < nb) bsum[t] = sm[t] - v;
}

__global__ void scan3_kernel(int* __restrict__ rowstart, int n, int E,
                             const int* __restrict__ bsum)
{
    int gid = blockIdx.x * TPB + threadIdx.x;
    if (gid < n) rowstart[gid] += bsum[blockIdx.x];
    if (gid == 0) rowstart[n] = E;
}

__global__ void fill_kernel(const int* __restrict__ rows, int E,
                            int* __restrict__ cursor, int* __restrict__ elist)
{
    int e = blockIdx.x * TPB + threadIdx.x;
    if (e >= E) return;
    int pos = atomicAdd(&cursor[rows[e]], 1);
    elist[pos] = e;
}

// ---------------------------------------------------------------------------
// Gather segment-sum: thread = (node, head).
// ---------------------------------------------------------------------------
__global__ __launch_bounds__(256) void gather_kernel(
    const float* __restrict__ P, const float* __restrict__ V,
    const int* __restrict__ cols,
    const int* __restrict__ rowstart, const int* __restrict__ elist,
    const float* __restrict__ Z, int N,
    float* __restrict__ out)
{
    int idx = blockIdx.x * TPB + threadIdx.x;
    if (idx >= N * 8) return;
    int node = idx >> 3, h = idx & 7;
    float invZ = 1.0f / Z[h];
    int p0 = rowstart[node], p1 = rowstart[node + 1];

    float4 a0 = make_float4(0,0,0,0), a1 = a0, a2 = a0, a3 = a0;
    for (int p = p0; p < p1; ++p) {
        int e = elist[p];
        int c = cols[e];
        float w = P[e * 8 + h] * invZ;
        const float4* v4 = reinterpret_cast<const float4*>(V) + (size_t)c * 32 + h * 4;
        float4 v0 = v4[0], v1 = v4[1], v2 = v4[2], v3 = v4[3];
        a0.x += w*v0.x; a0.y += w*v0.y; a0.z += w*v0.z; a0.w += w*v0.w;
        a1.x += w*v1.x; a1.y += w*v1.y; a1.z += w*v1.z; a1.w += w*v1.w;
        a2.x += w*v2.x; a2.y += w*v2.y; a2.z += w*v2.z; a2.w += w*v2.w;
        a3.x += w*v3.x; a3.y += w*v3.y; a3.z += w*v3.z; a3.w += w*v3.w;
    }
    float4* o4 = reinterpret_cast<float4*>(out) + (size_t)node * 32 + h * 4;
    o4[0] = a0; o4[1] = a1; o4[2] = a2; o4[3] = a3;
}

// ---------------------------------------------------------------------------
extern "C" void kernel_launch(void* const* d_in, const int* in_sizes, int n_in,
                              void* d_out, int out_size, void* d_ws, size_t ws_size,
                              hipStream_t stream)
{
    const float* feat = (const float*)d_in[0];
    const void*  eraw = d_in[1];
    const float* Wq = (const float*)d_in[2];
    const float* bq = (const float*)d_in[3];
    const float* Wk = (const float*)d_in[4];
    const float* bk = (const float*)d_in[5];
    const float* Wv = (const float*)d_in[6];
    const float* bv = (const float*)d_in[7];
    const float* Wo = (const float*)d_in[8];
    const float* bo = (const float*)d_in[9];

    const int N = in_sizes[0] / 128;
    const int E = in_sizes[1] / 2;
    const size_t NC = (size_t)N * 128;
    const int EH = E * 8;

    // Workspace layout
    float* Q   = (float*)d_ws;
    float* Km  = Q   + NC;
    float* Vm  = Km  + NC;
    float* ACC = Vm  + NC;
    float* P   = ACC + NC;                 // E*8 scores -> exp weights
    int*   EI  = (int*)(P + EH);           // int32 indices, 2*E
    short* WB  = (short*)(EI + 2 * E);     // 4 x 16384 bf16 weights (16B-aligned)
    unsigned* Mu   = (unsigned*)(WB + 65536);
    float*    Z    = (float*)(Mu + 8);
    int*      flag = (int*)(Z + 8);

    // CSR structures alias the Q buffer (Q is dead after edge_scores).
    int* deg      = (int*)Q;
    int* rowstart = deg + N;
    int* cursor   = rowstart + N + 1;
    int* bsum     = cursor + N;
    int* elist    = bsum + 512;

    hipMemsetAsync(Mu, 0, 8 * sizeof(unsigned) + 8 * sizeof(float) + sizeof(int), stream);

    // Normalize edge_index to int32; convert weights to bf16.
    detect_i64_kernel<<<1, 64, 0, stream>>>((const int*)eraw, flag);
    conv_idx_kernel<<<(2 * E + TPB - 1) / TPB, TPB, 0, stream>>>(eraw, 2 * E, flag, EI);
    wconv_kernel<<<256, TPB, 0, stream>>>(Wq, Wk, Wv, Wo, WB);

    // Fused Q/K/V projection (reads features once).
    const int gb64 = (N + 63) / 64;
    gemm_mfma_kernel<3><<<gb64, TPB, 0, stream>>>(feat, N, WB, bq, bk, bv, Q, Km, Vm);

    // Edge scores (uses Q, K).
    const int eb = (EH + TPB - 1) / TPB;
    edge_scores_kernel<<<eb, TPB, 0, stream>>>(Q, Km, EI, E, P);

    // CSR build (Q region now reusable).
    const int ebE = (E + TPB - 1) / TPB;
    const int nbS = (N + TPB - 1) / TPB;
    hipMemsetAsync(deg, 0, (size_t)N * sizeof(int), stream);
    hist_kernel<<<ebE, TPB, 0, stream>>>(EI, E, deg);
    scan1_kernel<<<nbS, TPB, 0, stream>>>(deg, N, rowstart, bsum);
    scan2_kernel<<<1, 512, 0, stream>>>(bsum, nbS);
    scan3_kernel<<<nbS, TPB, 0, stream>>>(rowstart, N, E, bsum);
    hipMemcpyAsync(cursor, rowstart, (size_t)N * sizeof(int),
                   hipMemcpyDeviceToDevice, stream);
    fill_kernel<<<ebE, TPB, 0, stream>>>(EI, E, cursor, elist);

    // Global per-head softmax.
    head_max_kernel<<<2048, TPB, 0, stream>>>(P, EH, Mu);
    exp_sum_kernel<<<2048, TPB, 0, stream>>>(P, EH, Mu, Z);

    // Gather segment-sum into ACC.
    const int gbN = (N * 8 + TPB - 1) / TPB;
    gather_kernel<<<gbN, TPB, 0, stream>>>(P, Vm, EI + E, rowstart, elist, Z, N, ACC);

    // Output projection.
    gemm_mfma_kernel<1><<<gb64, TPB, 0, stream>>>(ACC, N, WB + 3 * 16384, bo, bo, bo,
                                                  (float*)d_out, nullptr, nullptr);
}

// Round 4
// 401.733 us; speedup vs baseline: 13.1032x; 1.2757x over previous
//
#include <hip/hip_runtime.h>

// HyperbolicAttention: N=100000 nodes, C=128, H=8 heads, D=16, E=640000 edges.
// Round 4: per-W MFMA GEMMs (occupancy), bf16 Q/K/V storage (bytes),
//          single-pass online softmax stats, exp fused into gather.

#define TPB 256

typedef __attribute__((ext_vector_type(8))) short short8;
typedef __attribute__((ext_vector_type(4))) float f32x4;

// fp32 -> bf16 round-to-nearest-even
__device__ __forceinline__ short f2bf(float f) {
    unsigned u = __float_as_uint(f);
    u += 0x7fffu + ((u >> 16) & 1u);
    return (short)(u >> 16);
}
// bf16 -> fp32
__device__ __forceinline__ float bf2f(short s) {
    return __uint_as_float(((unsigned)(unsigned short)s) << 16);
}

// ---------------------------------------------------------------------------
// Convert the four 128x128 fp32 weight matrices to bf16 (row-major, packed).
// ---------------------------------------------------------------------------
__global__ void wconv_kernel(const float* __restrict__ W0, const float* __restrict__ W1,
                             const float* __restrict__ W2, const float* __restrict__ W3,
                             short* __restrict__ out)
{
    int i = blockIdx.x * TPB + threadIdx.x;   // 0..65535
    if (i >= 65536) return;
    const float* W = (i < 16384) ? W0 : (i < 32768) ? W1 : (i < 49152) ? W2 : W3;
    out[i] = f2bf(W[i & 16383]);
}

// ---------------------------------------------------------------------------
// Y = X @ W^T + b, X:[nrows,128] fp32, W:[128][128] bf16, one W per launch.
// mfma_f32_16x16x32_bf16; block = 4 waves, wave owns 16 rows x 128 cols.
// acc = 8 f32x4 (32 VGPR) -> high occupancy. OUT_BF16 selects output type.
// ---------------------------------------------------------------------------
template<bool OUT_BF16>
__global__ __launch_bounds__(256) void gemm_w_kernel(
    const float* __restrict__ X, int nrows,
    const short* __restrict__ Wb, const float* __restrict__ bias,
    void* __restrict__ Yv)
{
    const int tid  = threadIdx.x;
    const int wid  = tid >> 6;
    const int lane = tid & 63;
    const int l15  = lane & 15;
    const int lh   = lane >> 4;
    const int rowbase = blockIdx.x * 64 + wid * 16;

    f32x4 acc[8];
    #pragma unroll
    for (int n = 0; n < 8; ++n) acc[n] = (f32x4)0.f;

    const int arow = rowbase + l15;
    const bool rvalid = arow < nrows;
    const float4* Xr = reinterpret_cast<const float4*>(X + (size_t)arow * 128);

    #pragma unroll
    for (int kc = 0; kc < 4; ++kc) {
        short8 afrag = (short8)(short)0;
        if (rvalid) {
            float4 x0 = Xr[kc*8 + lh*2 + 0];
            float4 x1 = Xr[kc*8 + lh*2 + 1];
            afrag[0]=f2bf(x0.x); afrag[1]=f2bf(x0.y); afrag[2]=f2bf(x0.z); afrag[3]=f2bf(x0.w);
            afrag[4]=f2bf(x1.x); afrag[5]=f2bf(x1.y); afrag[6]=f2bf(x1.z); afrag[7]=f2bf(x1.w);
        }
        #pragma unroll
        for (int n = 0; n < 8; ++n) {
            short8 bfrag = *reinterpret_cast<const short8*>(
                Wb + (size_t)(n*16 + l15)*128 + kc*32 + lh*8);
            acc[n] = __builtin_amdgcn_mfma_f32_16x16x32_bf16(afrag, bfrag, acc[n], 0, 0, 0);
        }
    }

    #pragma unroll
    for (int n = 0; n < 8; ++n) {
        float bv = bias[n*16 + l15];
        #pragma unroll
        for (int j = 0; j < 4; ++j) {
            int r = rowbase + lh*4 + j;
            if (r < nrows) {
                float v = acc[n][j] + bv;
                if (OUT_BF16)
                    ((short*)Yv)[(size_t)r*128 + n*16 + l15] = f2bf(v);
                else
                    ((float*)Yv)[(size_t)r*128 + n*16 + l15] = v;
            }
        }
    }
}

// ---------------------------------------------------------------------------
// edge_index may arrive as int64 (reference) or int32. Detect on device.
// ---------------------------------------------------------------------------
__global__ void detect_i64_kernel(const int* __restrict__ raw, int* __restrict__ flag)
{
    if (blockIdx.x == 0 && threadIdx.x == 0) {
        int odd_nonzero = 0;
        for (int i = 0; i < 128; ++i)
            if (raw[2 * i + 1] != 0) odd_nonzero = 1;
        *flag = odd_nonzero ? 0 : 1;  // 1 => int64 layout
    }
}

__global__ void conv_idx_kernel(const void* __restrict__ raw, int n,
                                const int* __restrict__ flag, int* __restrict__ out)
{
    int i = blockIdx.x * TPB + threadIdx.x;
    if (i >= n) return;
    if (*flag) out[i] = (int)((const long long*)raw)[i];
    else       out[i] = ((const int*)raw)[i];
}

// ---------------------------------------------------------------------------
// Per-edge, per-head dot products from bf16 Q/K:
// S[e*8+h] = q[row[e],h,:] . k[col[e],h,:] / 4
// ---------------------------------------------------------------------------
__global__ void edge_scores_kernel(const short* __restrict__ Qb, const short* __restrict__ Kb,
                                   const int* __restrict__ ei, int E,
                                   float* __restrict__ S)
{
    int idx = blockIdx.x * TPB + threadIdx.x;
    if (idx >= E * 8) return;
    int e = idx >> 3, h = idx & 7;
    int r = ei[e], c = ei[E + e];
    const short8* q8 = reinterpret_cast<const short8*>(Qb) + (size_t)r * 16 + h * 2;
    const short8* k8 = reinterpret_cast<const short8*>(Kb) + (size_t)c * 16 + h * 2;
    short8 q0 = q8[0], q1 = q8[1], k0 = k8[0], k1 = k8[1];
    float dot = 0.f;
    #pragma unroll
    for (int i = 0; i < 8; ++i) {
        dot += bf2f(q0[i]) * bf2f(k0[i]);
        dot += bf2f(q1[i]) * bf2f(k1[i]);
    }
    S[idx] = dot * 0.25f;  // 1/sqrt(16)
}

// ---------------------------------------------------------------------------
// Single-pass online per-head softmax stats.
// Pass 1: per-block online (m,z) per head -> partials.
// Pass 2: one block combines 2048 partials -> M[8], Z[8] in MZ.
// Head-class invariant: all strides/offsets are multiples of 8, so thread t
// only ever touches head t&7.
// ---------------------------------------------------------------------------
__device__ __forceinline__ void online_combine(float& m, float& z, float m2, float z2)
{
    float M = fmaxf(m, m2);
    z = z * __expf(m - M) + z2 * __expf(m2 - M);
    m = M;
}

__global__ void stats_kernel(const float* __restrict__ S, int total,
                             float* __restrict__ mpart, float* __restrict__ zpart)
{
    int t = threadIdx.x;
    long long idx = (long long)blockIdx.x * TPB + t;
    long long stride = (long long)gridDim.x * TPB;   // multiple of 8
    float m = -3.0e38f, z = 0.f;
    for (; idx < total; idx += stride) {
        float s = S[idx];
        float M = fmaxf(m, s);
        z = z * __expf(m - M) + __expf(s - M);
        m = M;
    }
    __shared__ float sm_m[TPB], sm_z[TPB];
    sm_m[t] = m; sm_z[t] = z;
    __syncthreads();
    for (int off = 128; off >= 8; off >>= 1) {
        if (t < off) {
            float mm = sm_m[t + off], zz = sm_z[t + off];
            float M = fmaxf(sm_m[t], mm);
            sm_z[t] = sm_z[t] * __expf(sm_m[t] - M) + zz * __expf(mm - M);
            sm_m[t] = M;
        }
        __syncthreads();
    }
    if (t < 8) {
        mpart[blockIdx.x * 8 + t] = sm_m[t];
        zpart[blockIdx.x * 8 + t] = sm_z[t];
    }
}

__global__ void stats_reduce_kernel(const float* __restrict__ mpart,
                                    const float* __restrict__ zpart,
                                    int nb, float* __restrict__ MZ)
{
    int t = threadIdx.x;
    int h = t & 7, chunk = t >> 3;   // 32 chunks
    float m = -3.0e38f, z = 0.f;
    for (int i = chunk; i < nb; i += 32)
        online_combine(m, z, mpart[i * 8 + h], zpart[i * 8 + h]);
    __shared__ float sm_m[TPB], sm_z[TPB];
    sm_m[t] = m; sm_z[t] = z;
    __syncthreads();
    for (int off = 128; off >= 8; off >>= 1) {
        if (t < off) {
            float mm = sm_m[t + off], zz = sm_z[t + off];
            float M = fmaxf(sm_m[t], mm);
            sm_z[t] = sm_z[t] * __expf(sm_m[t] - M) + zz * __expf(mm - M);
            sm_m[t] = M;
        }
        __syncthreads();
    }
    if (t < 8) { MZ[t] = sm_m[t]; MZ[8 + t] = sm_z[t]; }
}

// ---------------------------------------------------------------------------
// CSR build: histogram by destination row, exclusive scan, binned fill.
// ---------------------------------------------------------------------------
__global__ void hist_kernel(const int* __restrict__ rows, int E, int* __restrict__ deg)
{
    int e = blockIdx.x * TPB + threadIdx.x;
    if (e < E) atomicAdd(&deg[rows[e]], 1);
}

__global__ void scan1_kernel(const int* __restrict__ deg, int n,
                             int* __restrict__ rowstart, int* __restrict__ bsum)
{
    __shared__ int sm[TPB];
    int t = threadIdx.x;
    int gid = blockIdx.x * TPB + t;
    int v = (gid < n) ? deg[gid] : 0;
    sm[t] = v;
    __syncthreads();
    for (int off = 1; off < TPB; off <<= 1) {
        int x = (t >= off) ? sm[t - off] : 0;
        __syncthreads();
        sm[t] += x;
        __syncthreads();
    }
    if (gid < n) rowstart[gid] = sm[t] - v;
    if (t == TPB - 1) bsum[blockIdx.x] = sm[t];
}

__global__ void scan2_kernel(int* __restrict__ bsum, int nb)
{
    __shared__ int sm[512];
    int t = threadIdx.x;
    int v = (t < nb) ? bsum[t] : 0;
    sm[t] = v;
    __syncthreads();
    for (int off = 1; off < 512; off <<= 1) {
        int x = (t >= off) ? sm[t - off] : 0;
        __syncthreads();
        sm[t] += x;
        __syncthreads();
    }
    if (t < nb) bsum[t] = sm[t] - v;
}

__global__ void scan3_kernel(int* __restrict__ rowstart, int n, int E,
                             const int* __restrict__ bsum)
{
    int gid = blockIdx.x * TPB + threadIdx.x;
    if (gid < n) rowstart[gid] += bsum[blockIdx.x];
    if (gid == 0) rowstart[n] = E;
}

__global__ void fill_kernel(const int* __restrict__ rows, int E,
                            int* __restrict__ cursor, int* __restrict__ elist)
{
    int e = blockIdx.x * TPB + threadIdx.x;
    if (e >= E) return;
    int pos = atomicAdd(&cursor[rows[e]], 1);
    elist[pos] = e;
}

// ---------------------------------------------------------------------------
// Gather segment-sum with fused softmax weight: thread = (node, head).
// out[node,h,:] = sum_e (exp(S[e,h]-M[h])/Z[h]) * V[col[e],h,:]
// ---------------------------------------------------------------------------
__global__ __launch_bounds__(256) void gather_kernel(
    const float* __restrict__ S, const short* __restrict__ Vb,
    const int* __restrict__ cols,
    const int* __restrict__ rowstart, const int* __restrict__ elist,
    const float* __restrict__ MZ, int N,
    float* __restrict__ out)
{
    int idx = blockIdx.x * TPB + threadIdx.x;
    if (idx >= N * 8) return;
    int node = idx >> 3, h = idx & 7;
    float M = MZ[h];
    float invZ = 1.0f / MZ[8 + h];
    int p0 = rowstart[node], p1 = rowstart[node + 1];

    float a[16];
    #pragma unroll
    for (int i = 0; i < 16; ++i) a[i] = 0.f;

    for (int p = p0; p < p1; ++p) {
        int e = elist[p];
        int c = cols[e];
        float w = __expf(S[e * 8 + h] - M) * invZ;
        const short8* v8 = reinterpret_cast<const short8*>(Vb) + (size_t)c * 16 + h * 2;
        short8 v0 = v8[0], v1 = v8[1];
        #pragma unroll
        for (int i = 0; i < 8; ++i) {
            a[i]     += w * bf2f(v0[i]);
            a[8 + i] += w * bf2f(v1[i]);
        }
    }
    float4* o4 = reinterpret_cast<float4*>(out) + (size_t)node * 32 + h * 4;
    o4[0] = make_float4(a[0],  a[1],  a[2],  a[3]);
    o4[1] = make_float4(a[4],  a[5],  a[6],  a[7]);
    o4[2] = make_float4(a[8],  a[9],  a[10], a[11]);
    o4[3] = make_float4(a[12], a[13], a[14], a[15]);
}

// ---------------------------------------------------------------------------
extern "C" void kernel_launch(void* const* d_in, const int* in_sizes, int n_in,
                              void* d_out, int out_size, void* d_ws, size_t ws_size,
                              hipStream_t stream)
{
    const float* feat = (const float*)d_in[0];
    const void*  eraw = d_in[1];
    const float* Wq = (const float*)d_in[2];
    const float* bq = (const float*)d_in[3];
    const float* Wk = (const float*)d_in[4];
    const float* bk = (const float*)d_in[5];
    const float* Wv = (const float*)d_in[6];
    const float* bv = (const float*)d_in[7];
    const float* Wo = (const float*)d_in[8];
    const float* bo = (const float*)d_in[9];

    const int N = in_sizes[0] / 128;
    const int E = in_sizes[1] / 2;
    const size_t NC = (size_t)N * 128;
    const int EH = E * 8;

    // Workspace layout
    short* Qb  = (short*)d_ws;             // NC bf16
    short* Kb  = Qb + NC;                  // NC bf16
    short* Vb  = Kb + NC;                  // NC bf16
    float* ACC = (float*)(Vb + NC);        // NC fp32
    float* S   = ACC + NC;                 // E*8 raw scores
    int*   EI  = (int*)(S + EH);           // int32 indices, 2*E
    short* WB  = (short*)(EI + 2 * E);     // 4 x 16384 bf16 weights
    float* mpart = (float*)(WB + 65536);   // 2048*8
    float* zpart = mpart + 2048 * 8;       // 2048*8
    float* MZ    = zpart + 2048 * 8;       // 16: M[8], Z[8]
    int*   flag  = (int*)(MZ + 16);

    // CSR structures alias the Qb buffer (dead after edge_scores).
    int* deg      = (int*)Qb;
    int* rowstart = deg + N;
    int* cursor   = rowstart + N + 1;
    int* bsum     = cursor + N;
    int* elist    = bsum + 512;

    // Normalize edge_index to int32; convert weights to bf16.
    detect_i64_kernel<<<1, 64, 0, stream>>>((const int*)eraw, flag);
    conv_idx_kernel<<<(2 * E + TPB - 1) / TPB, TPB, 0, stream>>>(eraw, 2 * E, flag, EI);
    wconv_kernel<<<256, TPB, 0, stream>>>(Wq, Wk, Wv, Wo, WB);

    // Q/K/V projections (bf16 outputs), one W per launch for occupancy.
    const int gb64 = (N + 63) / 64;
    gemm_w_kernel<true><<<gb64, TPB, 0, stream>>>(feat, N, WB,             bq, Qb);
    gemm_w_kernel<true><<<gb64, TPB, 0, stream>>>(feat, N, WB + 16384,     bk, Kb);
    gemm_w_kernel<true><<<gb64, TPB, 0, stream>>>(feat, N, WB + 2 * 16384, bv, Vb);

    // Edge scores (bf16 Q/K).
    const int eb = (EH + TPB - 1) / TPB;
    edge_scores_kernel<<<eb, TPB, 0, stream>>>(Qb, Kb, EI, E, S);

    // CSR build (Qb region now reusable).
    const int ebE = (E + TPB - 1) / TPB;
    const int nbS = (N + TPB - 1) / TPB;
    hipMemsetAsync(deg, 0, (size_t)N * sizeof(int), stream);
    hist_kernel<<<ebE, TPB, 0, stream>>>(EI, E, deg);
    scan1_kernel<<<nbS, TPB, 0, stream>>>(deg, N, rowstart, bsum);
    scan2_kernel<<<1, 512, 0, stream>>>(bsum, nbS);
    scan3_kernel<<<nbS, TPB, 0, stream>>>(rowstart, N, E, bsum);
    hipMemcpyAsync(cursor, rowstart, (size_t)N * sizeof(int),
                   hipMemcpyDeviceToDevice, stream);
    fill_kernel<<<ebE, TPB, 0, stream>>>(EI, E, cursor, elist);

    // Global per-head softmax stats (single pass + tiny combine).
    stats_kernel<<<2048, TPB, 0, stream>>>(S, EH, mpart, zpart);
    stats_reduce_kernel<<<1, TPB, 0, stream>>>(mpart, zpart, 2048, MZ);

    // Gather segment-sum with fused exp/normalize.
    const int gbN = (N * 8 + TPB - 1) / TPB;
    gather_kernel<<<gbN, TPB, 0, stream>>>(S, Vb, EI + E, rowstart, elist, MZ, N, ACC);

    // Output projection (fp32 output).
    gemm_w_kernel<false><<<gb64, TPB, 0, stream>>>(ACC, N, WB + 3 * 16384, bo, (float*)d_out);
}